// Round 1
// baseline (224.945 us; speedup 1.0000x reference)
//
#include <hip/hip_runtime.h>

// RoiCut: out[i, c, y, x] = fm[assoc[i], c, y0_i + y, x0_i + x]
// fm: [8, 256, 200, 200] fp32, boxes_yx: [512, 2] int32 (y0, x0), assoc: [512] int32
// out: [512, 256, 32, 32] fp32

constexpr int C_   = 256;
constexpr int H_   = 200;
constexpr int W_   = 200;
constexpr int BOX_ = 32;

__global__ __launch_bounds__(256) void roicut_kernel(
    const float* __restrict__ fm,
    const int*   __restrict__ boxes,
    const int*   __restrict__ assoc,
    float*       __restrict__ out,
    int total_vec4)
{
    int idx = blockIdx.x * blockDim.x + threadIdx.x;
    if (idx >= total_vec4) return;

    int e = idx << 2;                 // element index of the first of 4
    // decode: e = (((i*256 + c)*32 + y)*32 + x)
    int i = e >> 18;                  // box index (2^18 elems per box)
    int c = (e >> 10) & 255;          // channel
    int y = (e >> 5)  & 31;           // row within crop
    int x = e & 31;                   // col within crop (0,4,8,...,28)

    int a  = assoc[i];
    int y0 = boxes[2 * i];
    int x0 = boxes[2 * i + 1];
    // clip_boxes=True semantics
    y0 = min(max(y0, 0), H_ - BOX_);
    x0 = min(max(x0, 0), W_ - BOX_);

    const float* src = fm + ((((size_t)a * C_ + c) * H_ + (y0 + y)) * W_ + (x0 + x));

    float4 v;
    v.x = src[0];
    v.y = src[1];
    v.z = src[2];
    v.w = src[3];

    *reinterpret_cast<float4*>(out + e) = v;
}

extern "C" void kernel_launch(void* const* d_in, const int* in_sizes, int n_in,
                              void* d_out, int out_size, void* d_ws, size_t ws_size,
                              hipStream_t stream) {
    const float* fm    = (const float*)d_in[0];
    const int*   boxes = (const int*)d_in[1];
    const int*   assoc = (const int*)d_in[2];
    float*       out   = (float*)d_out;

    // out_size = 512 * 256 * 32 * 32 = 134217728 elements
    int total_vec4 = out_size >> 2;   // 4 elems per thread
    int block = 256;
    int grid  = (total_vec4 + block - 1) / block;

    roicut_kernel<<<grid, block, 0, stream>>>(fm, boxes, assoc, out, total_vec4);
}

// Round 2
// 202.426 us; speedup vs baseline: 1.1112x; 1.1112x over previous
//
#include <hip/hip_runtime.h>

// RoiCut: out[i, c, y, x] = fm[assoc[i], c, y0_i + y, x0_i + x]
// fm: [8, 256, 200, 200] fp32, boxes_yx: [512, 2] int32 (y0, x0), assoc: [512] int32
// out: [512, 256, 32, 32] fp32
//
// Strategy: boxes are processed in (assoc, y0, x0)-sorted order so that
// concurrently-resident blocks read from the same sample slice (~41 MB << 256 MB L3),
// turning inter-box overlap into L3 hits instead of repeated HBM fetches.
// A 1-block bitonic sort produces the permutation in d_ws.

constexpr int C_   = 256;
constexpr int H_   = 200;
constexpr int W_   = 200;
constexpr int BOX_ = 32;
constexpr int N_   = 512;

__global__ __launch_bounds__(512) void sort_boxes_kernel(
    const int* __restrict__ boxes,
    const int* __restrict__ assoc,
    int*       __restrict__ perm)
{
    __shared__ unsigned int key[N_];
    int t = threadIdx.x;  // 512 threads, one per box

    int y0 = boxes[2 * t];
    int x0 = boxes[2 * t + 1];
    y0 = min(max(y0, 0), H_ - BOX_);
    x0 = min(max(x0, 0), W_ - BOX_);
    unsigned int a = (unsigned int)assoc[t];
    // key: [assoc:3 | y0:8 | x0:8 | idx:9]  -- unique keys -> deterministic sort
    key[t] = (a << 25) | ((unsigned int)y0 << 17) | ((unsigned int)x0 << 9) | (unsigned int)t;
    __syncthreads();

    // bitonic sort, 512 elements
    for (int k = 2; k <= N_; k <<= 1) {
        for (int j = k >> 1; j > 0; j >>= 1) {
            int ixj = t ^ j;
            if (ixj > t) {
                unsigned int va = key[t], vb = key[ixj];
                bool asc = ((t & k) == 0);
                if ((va > vb) == asc) { key[t] = vb; key[ixj] = va; }
            }
            __syncthreads();
        }
    }

    perm[t] = (int)(key[t] & 511u);
}

__global__ __launch_bounds__(256) void roicut_kernel(
    const float* __restrict__ fm,
    const int*   __restrict__ boxes,
    const int*   __restrict__ assoc,
    const int*   __restrict__ perm,
    float*       __restrict__ out)
{
    int b = blockIdx.x;
    int s = b >> 8;        // sorted box slot
    int c = b & 255;       // channel (one block = one (box, channel) tile)
    int t = threadIdx.x;   // 256 threads cover 32x32 crop, 4 floats each

    int i  = perm[s];      // actual box index (uniform per block -> scalar)
    int a  = assoc[i];
    int y0 = boxes[2 * i];
    int x0 = boxes[2 * i + 1];
    y0 = min(max(y0, 0), H_ - BOX_);
    x0 = min(max(x0, 0), W_ - BOX_);

    int y = t >> 3;            // 0..31
    int x = (t & 7) << 2;      // 0,4,...,28

    const float* src = fm + ((((size_t)a * C_ + c) * H_ + (y0 + y)) * W_ + (x0 + x));
    float4 v;
    v.x = src[0];
    v.y = src[1];
    v.z = src[2];
    v.w = src[3];

    float* dst = out + (((size_t)i << 18) | (unsigned)(c << 10) | (unsigned)(t << 2));
    *reinterpret_cast<float4*>(dst) = v;
}

extern "C" void kernel_launch(void* const* d_in, const int* in_sizes, int n_in,
                              void* d_out, int out_size, void* d_ws, size_t ws_size,
                              hipStream_t stream) {
    const float* fm    = (const float*)d_in[0];
    const int*   boxes = (const int*)d_in[1];
    const int*   assoc = (const int*)d_in[2];
    float*       out   = (float*)d_out;
    int*         perm  = (int*)d_ws;   // 512 ints

    sort_boxes_kernel<<<1, N_, 0, stream>>>(boxes, assoc, perm);

    int grid = N_ * C_;  // 131072 blocks, one per (box, channel)
    roicut_kernel<<<grid, 256, 0, stream>>>(fm, boxes, assoc, perm, out);
}